// Round 19
// baseline (553.839 us; speedup 1.0000x reference)
//
#include <hip/hip_runtime.h>

#define T_N 256
#define U_N 512
#define H_N 64
#define P_N 1024

typedef __attribute__((ext_vector_type(8))) short short8;
typedef __attribute__((ext_vector_type(4))) short short4v;
typedef __attribute__((ext_vector_type(4))) float f32x4;
typedef __attribute__((ext_vector_type(4))) unsigned int u32x4;

#define MFMA __builtin_amdgcn_mfma_f32_16x16x32_bf16

// LDS-only barrier: does NOT drain vmcnt.
#define LGKM_BARRIER() asm volatile("s_waitcnt lgkmcnt(0)\ns_barrier" ::: "memory")

__device__ __forceinline__ float fastrcp(float x) { return __builtin_amdgcn_rcpf(x); }
__device__ __forceinline__ float fastsqrt(float x) { return __builtin_amdgcn_sqrtf(x); }

__device__ __forceinline__ short f2bf(float f) {
  union { float f; unsigned u; } v; v.f = f;
  unsigned r = v.u + 0x7FFFu + ((v.u >> 16) & 1u);
  return (short)(r >> 16);
}

__device__ __forceinline__ unsigned cvtpk(float lo, float hi) {
  unsigned r;
  asm("v_cvt_pk_bf16_f32 %0, %1, %2" : "=v"(r) : "v"(lo), "v"(hi));
  return r;
}

__device__ __forceinline__ short8 pack8(float4 a, float4 b) {
  union { unsigned u[4]; short8 s; } z;
  z.u[0] = cvtpk(a.x, a.y); z.u[1] = cvtpk(a.z, a.w);
  z.u[2] = cvtpk(b.x, b.y); z.u[3] = cvtpk(b.z, b.w);
  return z.s;
}

__device__ __forceinline__ float bfu_lo(unsigned u) {
  union { unsigned x; float f; } v; v.x = u << 16; return v.f;
}
__device__ __forceinline__ float bfu_hi(unsigned u) {
  union { unsigned x; float f; } v; v.x = u & 0xffff0000u; return v.f;
}

// ---- pack Wx/Wh scan frags + fc_W[0:64] frags + ub (merged) -----------------
__global__ __launch_bounds__(256) void k_pack(
    const float* __restrict__ Wx, const float* __restrict__ Wh,
    const float* __restrict__ fcW, const int* __restrict__ active_user,
    const float* __restrict__ user_emb, const float* __restrict__ fcb,
    short* __restrict__ wxp, short* __restrict__ whp, short* __restrict__ bp,
    float* __restrict__ ub) {
  int tid = threadIdx.x;
  if (blockIdx.x < 12) {
    int idx = blockIdx.x * 256 + tid;  // 3072 = 2*1536
    int m = idx / 1536;
    int r = idx % 1536;
    const float* W = m ? Wh : Wx;
    short* op = m ? whp : wxp;
    int ks = r / 768, lk = (r / 192) & 3, g = r % 192;
#pragma unroll
    for (int e = 0; e < 8; ++e)
      op[(size_t)r * 8 + e] = f2bf(W[(ks * 32 + lk * 8 + e) * 192 + g]);
  } else if (blockIdx.x < 44) {
    int sidx = (blockIdx.x - 12) * 256 + tid;  // 0..8191
    int s = sidx & 1023;
    int kg = (sidx >> 10) & 3;
    int ks = sidx >> 12;
    int L = (s & ~63) + 4 * (s & 15) + ((s >> 4) & 3);
#pragma unroll
    for (int e = 0; e < 8; ++e) {
      int k = ks * 32 + kg * 8 + e;
      bp[((size_t)((ks * 4 + kg) * P_N + s)) * 8 + e] = f2bf(fcW[k * P_N + L]);
    }
  } else {
    int u = blockIdx.x - 44;
    __shared__ float pu[H_N];
    if (tid < H_N) pu[tid] = user_emb[active_user[u] * H_N + tid];
    __syncthreads();
    for (int p = tid; p < P_N; p += 256) {
      float acc = fcb[p];
#pragma unroll
      for (int k = 0; k < H_N; ++k) acc += pu[k] * fcW[(H_N + k) * P_N + p];
      ub[u * P_N + p] = acc;
    }
  }
}

// ---- gx precompute (TRANSPOSED): C[gate][user]; A = Wx^T frag, B = emb ------
__global__ __launch_bounds__(256) void k_gx(
    const int* __restrict__ x, const float* __restrict__ poi_emb,
    const short* __restrict__ wxp, const float* __restrict__ b,
    char* __restrict__ gxp) {
  int wave = threadIdx.x >> 6, lane = threadIdx.x & 63;
  int lr = lane & 15, lk = lane >> 4;
  int tile = blockIdx.x * 4 + wave;   // 0..8191
  int row = tile * 16 + lr;           // flat t*512+u; user = lr
  int xv = x[row];
  const float* pb = poi_emb + (size_t)xv * H_N + lk * 8;
  float4 v0 = *(const float4*)pb, v1 = *(const float4*)(pb + 4);
  float4 v2 = *(const float4*)(pb + 32), v3 = *(const float4*)(pb + 36);
  short8 ax0 = pack8(v0, v1), ax1 = pack8(v2, v3);  // B-frag: col=user, k=h
#pragma unroll
  for (int j = 0; j < 12; ++j) {
    f32x4 acc;
#pragma unroll
    for (int e = 0; e < 4; ++e) acc[e] = b[16 * j + 4 * lk + e];
    short8 bf0 = *(const short8*)&wxp[((size_t)((0 * 4 + lk) * 192 + 16 * j + lr)) * 8];
    short8 bf1 = *(const short8*)&wxp[((size_t)((1 * 4 + lk) * 192 + 16 * j + lr)) * 8];
    acc = MFMA(bf0, ax0, acc, 0, 0, 0);   // A = Wx^T frag, B = emb frag
    acc = MFMA(bf1, ax1, acc, 0, 0, 0);
    uint2 pk;
    pk.x = cvtpk(acc[0], acc[1]);
    pk.y = cvtpk(acc[2], acc[3]);
    *(uint2*)(gxp + (((size_t)tile * 12 + j) * 64 + lane) * 8) = pk;
  }
}

// ---- GRU scan (transposed) + LDS-staged coalesced flush.
//      PMC PROBE: time-loop run 3x (idempotent reps). ------------------------
__global__ __launch_bounds__(256) void k_scan3(
    const char* __restrict__ gxp, const float* __restrict__ h0,
    const short* __restrict__ whp, short* __restrict__ out_tr,
    float* __restrict__ hT) {
  int ublk = blockIdx.x;
  int u0 = ublk * 16;
  int tid = threadIdx.x;
  int w = tid >> 6, lane = tid & 63, lr = lane & 15, q = lane >> 4;
  __shared__ __align__(16) unsigned short h16[2][16][68];   // ping-pong h
  __shared__ __align__(16) unsigned short flsh[16][520];    // flush stage, 1040B/user
  int sgr = 16 * w, sgz = 64 + 16 * w, sgn = 128 + 16 * w;
  short8 fhr[2], fhz[2], fhn[2];  // A-frags (Wh^T): row=gate, k=h
#pragma unroll
  for (int ks = 0; ks < 2; ++ks) {
    size_t base = (size_t)((ks * 4 + q) * 192) * 8;
    fhr[ks] = *(const short8*)&whp[base + (size_t)(sgr + lr) * 8];
    fhz[ks] = *(const short8*)&whp[base + (size_t)(sgz + lr) * 8];
    fhn[ks] = *(const short8*)&whp[base + (size_t)(sgn + lr) * 8];
  }
  const char* gbase = gxp + (((size_t)ublk * 12 + w) * 64 + lane) * 8;
  uint2 pr0, pr1, pr2, pr3, pr4, pr5, pr6, pr7;
  uint2 pz0, pz1, pz2, pz3, pz4, pz5, pz6, pz7;
  uint2 pn0, pn1, pn2, pn3, pn4, pn5, pn6, pn7;
  float hp[4];
  short8 bh0, bh1;
  float hb[4][8];  // static-index only
#define PF(sl, tt) { size_t o = (size_t)(tt) * 196608; \
    pr##sl = *(const uint2*)(gbase + o); \
    pz##sl = *(const uint2*)(gbase + o + 2048); \
    pn##sl = *(const uint2*)(gbase + o + 4096); }
#define GATE(E, TB) { \
      float r = fastrcp(1.f + __expf(-accr[E])); \
      float z = fastrcp(1.f + __expf(-accz[E])); \
      float npre = __builtin_fmaf(r, accnh[E], accnx[E]); \
      float e2 = __expf(2.f * npre); \
      float n = 1.f - 2.f * fastrcp(e2 + 1.f); \
      float hn = __builtin_fmaf(z, n - hp[E], hp[E]); \
      hp[E] = hn; \
      hb[E][TB] = hn; }
#define BODY(TB, SL) { \
      f32x4 accr = {bfu_lo(pr##SL.x), bfu_hi(pr##SL.x), bfu_lo(pr##SL.y), bfu_hi(pr##SL.y)}; \
      f32x4 accz = {bfu_lo(pz##SL.x), bfu_hi(pz##SL.x), bfu_lo(pz##SL.y), bfu_hi(pz##SL.y)}; \
      f32x4 accnx = {bfu_lo(pn##SL.x), bfu_hi(pn##SL.x), bfu_lo(pn##SL.y), bfu_hi(pn##SL.y)}; \
      f32x4 accnh = {0.f, 0.f, 0.f, 0.f}; \
      int tpf = t8 + TB + 8; if (tpf > 255) tpf = 255; \
      PF(SL, tpf) \
      accr = MFMA(fhr[0], bh0, accr, 0, 0, 0); \
      accr = MFMA(fhr[1], bh1, accr, 0, 0, 0); \
      accz = MFMA(fhz[0], bh0, accz, 0, 0, 0); \
      accz = MFMA(fhz[1], bh1, accz, 0, 0, 0); \
      accnh = MFMA(fhn[0], bh0, accnh, 0, 0, 0); \
      accnh = MFMA(fhn[1], bh1, accnh, 0, 0, 0); \
      GATE(0, TB) GATE(1, TB) GATE(2, TB) GATE(3, TB) \
      { \
        uint2 pk; \
        pk.x = cvtpk(hp[0], hp[1]); \
        pk.y = cvtpk(hp[2], hp[3]); \
        *(uint2*)&h16[(TB) & 1][lr][16 * w + 4 * q] = pk; \
      } \
      LGKM_BARRIER(); \
      bh0 = *(const short8*)&h16[(TB) & 1][lr][8 * q]; \
      bh1 = *(const short8*)&h16[(TB) & 1][lr][32 + 8 * q]; }
  for (int rep = 0; rep < 3; ++rep) {
    __syncthreads();  // protect h16/flsh reinit vs prior rep
#pragma unroll
    for (int e = 0; e < 4; ++e)
      hp[e] = h0[(size_t)(u0 + lr) * H_N + 16 * w + 4 * q + e];
    {
      uint2 pk;
      pk.x = cvtpk(hp[0], hp[1]);
      pk.y = cvtpk(hp[2], hp[3]);
      *(uint2*)&h16[1][lr][16 * w + 4 * q] = pk;
    }
    __syncthreads();
    bh0 = *(const short8*)&h16[1][lr][8 * q];
    bh1 = *(const short8*)&h16[1][lr][32 + 8 * q];
    PF(0, 0) PF(1, 1) PF(2, 2) PF(3, 3) PF(4, 4) PF(5, 5) PF(6, 6) PF(7, 7)
    for (int t8 = 0; t8 < T_N; t8 += 8) {
      BODY(0, 0) BODY(1, 1) BODY(2, 2) BODY(3, 3)
      BODY(4, 4) BODY(5, 5) BODY(6, 6) BODY(7, 7)
      // flush: stage hb -> flsh (bf16), barrier, coalesced 1KB/wave readout
      {
#pragma unroll
        for (int e = 0; e < 4; ++e) {
          u32x4 pk;
          pk[0] = cvtpk(hb[e][0], hb[e][1]);
          pk[1] = cvtpk(hb[e][2], hb[e][3]);
          pk[2] = cvtpk(hb[e][4], hb[e][5]);
          pk[3] = cvtpk(hb[e][6], hb[e][7]);
          *(u32x4*)&flsh[lr][(16 * w + 4 * q + e) * 8] = pk;
        }
        LGKM_BARRIER();
        int tb = t8 >> 3;
#pragma unroll
        for (int pp = 0; pp < 4; ++pp) {
          int p = pp * 256 + tid;
          int uu = p >> 6, hh = p & 63;
          u32x4 v = *(const u32x4*)&flsh[uu][hh * 8];
          __builtin_nontemporal_store(
              v, (u32x4*)&out_tr[((((size_t)(u0 + uu)) * 32 + tb) * 64 + hh) * 8]);
        }
      }
    }
#pragma unroll
    for (int e = 0; e < 4; ++e)
      hT[(size_t)(u0 + lr) * H_N + 16 * w + 4 * q + e] = hp[e];  // exact f32
  }
}

// ---- decay-weighted sum as causal MFMA GEMM; factored trig/exp w-compute ----
__global__ __launch_bounds__(256, 4) void k_stage2(
    const float* __restrict__ t, const float* __restrict__ s,
    const short* __restrict__ out_tr, short* __restrict__ apk) {
  int u = blockIdx.x;
  int tid = threadIdx.x;
  __shared__ __align__(16) unsigned short wlT[16][264];  // [i'][j] bf16
  __shared__ __align__(8) float csU[T_N][2];
  __shared__ __align__(8) float seU[T_N][2];
  __shared__ float eU[T_N];
  float cj, sj, Fj, sx, sy;
  {
    int jr = tid;
    float tj = t[jr * U_N + u];
    cj = __cosf(tj * 7.2722052166430395e-05f);
    sj = __sinf(tj * 7.2722052166430395e-05f);
    float ej = __expf(tj * -1.1574074074074074e-06f);
    Fj = __expf(tj * 1.1574074074074074e-06f);
    csU[jr][0] = cj; csU[jr][1] = sj;
    eU[jr] = ej;
    sx = s[((size_t)jr * U_N + u) * 2];
    sy = s[((size_t)jr * U_N + u) * 2 + 1];
    seU[jr][0] = sx; seU[jr][1] = sy;
  }
  __syncthreads();
  int lane = tid & 63, wv = tid >> 6;
  int lr = lane & 15, lk = lane >> 4;
  int j = tid;
  const short* obase = out_tr + (size_t)u * 32 * 64 * 8;  // [tb][h][8]
  short8 ones;
#pragma unroll
  for (int e = 0; e < 8; ++e) ones[e] = (short)0x3F80;
  for (int c = 0; c < 16; ++c) {
    int nk = (c + 2) >> 1;
    if (wv * 64 < nk * 32) {
#pragma unroll
      for (int iqq = 0; iqq < 16; ++iqq) {
        int i = c * 16 + iqq;
        float ci = csU[i][0], si = csU[i][1];
        float ei = eU[i];
        float dx = seU[i][0] - sx, dy = seU[i][1] - sy;
        float dsn = fastsqrt(__builtin_fmaf(dx, dx, dy * dy));
        float fs = __expf(-100.0f * dsn);
        float ctm = __builtin_fmaf(ci, cj, si * sj);
        float ft2 = __builtin_fmaf(0.5f, ctm, 0.5f);
        float ww = __builtin_fmaf(ft2 * (ei * Fj), fs, 1e-10f);
        ww = (j <= i) ? ww : 0.0f;
        wlT[iqq][j] = (unsigned short)cvtpk(ww, ww);
      }
    }
    __syncthreads();  // B1
    f32x4 acc = {0.f, 0.f, 0.f, 0.f};
    f32x4 acc1 = {0.f, 0.f, 0.f, 0.f};
    for (int kk = 0; kk < nk; ++kk) {
      short8 aw = *(const short8*)&wlT[lr][kk * 32 + 8 * lk];
      short8 bo = *(const short8*)&obase[(((kk * 4 + lk) * 64) + 16 * wv + lr) * 8];
      acc = MFMA(aw, bo, acc, 0, 0, 0);
      acc1 = MFMA(aw, ones, acc1, 0, 0, 0);
    }
#pragma unroll
    for (int e = 0; e < 4; ++e) {
      int i = c * 16 + 4 * lk + e;
      float val = acc[e] * fastrcp(acc1[e]);
      apk[((size_t)i * U_N + u) * H_N + 16 * wv + lr] = f2bf(val);
    }
    __syncthreads();  // B2
  }
}

// ---- FC: grid dim3(1024,8) bm-fastest -> per-XCD apk slice is L2-resident ---
__global__ __launch_bounds__(256) void k_fc(
    const short* __restrict__ apk, const short* __restrict__ Bp,
    const float* __restrict__ ub, float* __restrict__ C) {
  int bm = blockIdx.x, bn = blockIdx.y;
  int tid = threadIdx.x;
  int wave = tid >> 6, lane = tid & 63;
  int wm = wave >> 1, wn = wave & 1;
  int row0 = bm * 128 + wm * 64;
  int col0 = bn * 128 + wn * 64;
  int lr = lane & 15, lk = lane >> 4;
  f32x4 acc[4][4] = {};
#pragma unroll
  for (int ks = 0; ks < 2; ++ks) {
    short8 af[4];
#pragma unroll
    for (int m = 0; m < 4; ++m)
      af[m] = *(const short8*)&apk[((size_t)(row0 + m * 16 + lr)) * H_N + ks * 32 + lk * 8];
#pragma unroll
    for (int n = 0; n < 4; ++n) {
      short8 bf = *(const short8*)&Bp[((size_t)((ks * 4 + lk) * P_N + col0 + n * 16 + lr)) * 8];
#pragma unroll
      for (int m = 0; m < 4; ++m)
        acc[m][n] = MFMA(af[m], bf, acc[m][n], 0, 0, 0);
    }
  }
#pragma unroll
  for (int m = 0; m < 4; ++m) {
    int rbase = row0 + m * 16 + lk * 4;
#pragma unroll
    for (int r = 0; r < 4; ++r) {
      int row = rbase + r;
      int uu = row & (U_N - 1);
      f32x4 ubv = *(const f32x4*)&ub[(size_t)uu * P_N + col0 + 4 * lr];
      f32x4 v;
      v[0] = acc[m][0][r] + ubv[0];
      v[1] = acc[m][1][r] + ubv[1];
      v[2] = acc[m][2][r] + ubv[2];
      v[3] = acc[m][3][r] + ubv[3];
      __builtin_nontemporal_store(v, (f32x4*)&C[(size_t)row * P_N + col0 + 4 * lr]);
    }
  }
}

extern "C" void kernel_launch(void* const* d_in, const int* in_sizes, int n_in,
                              void* d_out, int out_size, void* d_ws, size_t ws_size,
                              hipStream_t stream) {
  const int*   x           = (const int*)d_in[0];
  const float* t           = (const float*)d_in[1];
  const float* s           = (const float*)d_in[3];
  const float* h0          = (const float*)d_in[5];
  const int*   active_user = (const int*)d_in[6];
  const float* poi_emb     = (const float*)d_in[7];
  const float* user_emb    = (const float*)d_in[8];
  const float* Wx          = (const float*)d_in[9];
  const float* Wh          = (const float*)d_in[10];
  const float* b           = (const float*)d_in[11];
  const float* fcW         = (const float*)d_in[12];
  const float* fcb         = (const float*)d_in[13];

  float* y_out = (float*)d_out;
  float* hT = y_out + (size_t)T_N * U_N * P_N;

  char* ws = (char*)d_ws;
  short* out_tr = (short*)ws;                           // 16,777,216 B
  char*  gxp    = ws + 16777216;                        // 50,331,648 B (dead after scan)
  short* apk    = (short*)(ws + 16777216);              // OVERLAPS gxp
  float* ub     = (float*)(ws + 67108864);              // 2,097,152 B
  short* bp     = (short*)(ws + 69206016);              // 131,072 B
  short* wxp    = (short*)(ws + 69337088);              // 24,576 B
  short* whp    = (short*)(ws + 69361664);              // 24,576 B

  k_pack<<<556, 256, 0, stream>>>(Wx, Wh, fcW, active_user, user_emb, fcb,
                                  wxp, whp, bp, ub);
  k_gx<<<2048, 256, 0, stream>>>(x, poi_emb, wxp, b, gxp);
  // PMC PROBE: k_scan3 runs its time-loop 3x internally (idempotent) so it
  // surfaces in the top-5 with counters. Remove the reps next round.
  k_scan3<<<32, 256, 0, stream>>>(gxp, h0, whp, out_tr, hT);
  k_stage2<<<U_N, 256, 0, stream>>>(t, s, out_tr, apk);
  k_fc<<<dim3(1024, 8), 256, 0, stream>>>(apk, bp, ub, y_out);
}

// Round 20
// 363.757 us; speedup vs baseline: 1.5226x; 1.5226x over previous
//
#include <hip/hip_runtime.h>

#define T_N 256
#define U_N 512
#define H_N 64
#define P_N 1024

typedef __attribute__((ext_vector_type(8))) short short8;
typedef __attribute__((ext_vector_type(4))) short short4v;
typedef __attribute__((ext_vector_type(4))) float f32x4;
typedef __attribute__((ext_vector_type(4))) unsigned int u32x4;

#define MFMA __builtin_amdgcn_mfma_f32_16x16x32_bf16

// LDS-only barrier: does NOT drain vmcnt.
#define LGKM_BARRIER() asm volatile("s_waitcnt lgkmcnt(0)\ns_barrier" ::: "memory")

__device__ __forceinline__ float fastrcp(float x) { return __builtin_amdgcn_rcpf(x); }
__device__ __forceinline__ float fastsqrt(float x) { return __builtin_amdgcn_sqrtf(x); }

__device__ __forceinline__ short f2bf(float f) {
  union { float f; unsigned u; } v; v.f = f;
  unsigned r = v.u + 0x7FFFu + ((v.u >> 16) & 1u);
  return (short)(r >> 16);
}

__device__ __forceinline__ unsigned cvtpk(float lo, float hi) {
  unsigned r;
  asm("v_cvt_pk_bf16_f32 %0, %1, %2" : "=v"(r) : "v"(lo), "v"(hi));
  return r;
}

__device__ __forceinline__ short8 pack8(float4 a, float4 b) {
  union { unsigned u[4]; short8 s; } z;
  z.u[0] = cvtpk(a.x, a.y); z.u[1] = cvtpk(a.z, a.w);
  z.u[2] = cvtpk(b.x, b.y); z.u[3] = cvtpk(b.z, b.w);
  return z.s;
}

__device__ __forceinline__ float bfu_lo(unsigned u) {
  union { unsigned x; float f; } v; v.x = u << 16; return v.f;
}
__device__ __forceinline__ float bfu_hi(unsigned u) {
  union { unsigned x; float f; } v; v.x = u & 0xffff0000u; return v.f;
}

// ---- pack Wx/Wh scan frags + fc_W[0:64] frags + ub (merged) -----------------
__global__ __launch_bounds__(256) void k_pack(
    const float* __restrict__ Wx, const float* __restrict__ Wh,
    const float* __restrict__ fcW, const int* __restrict__ active_user,
    const float* __restrict__ user_emb, const float* __restrict__ fcb,
    short* __restrict__ wxp, short* __restrict__ whp, short* __restrict__ bp,
    float* __restrict__ ub) {
  int tid = threadIdx.x;
  if (blockIdx.x < 12) {
    int idx = blockIdx.x * 256 + tid;  // 3072 = 2*1536
    int m = idx / 1536;
    int r = idx % 1536;
    const float* W = m ? Wh : Wx;
    short* op = m ? whp : wxp;
    int ks = r / 768, lk = (r / 192) & 3, g = r % 192;
#pragma unroll
    for (int e = 0; e < 8; ++e)
      op[(size_t)r * 8 + e] = f2bf(W[(ks * 32 + lk * 8 + e) * 192 + g]);
  } else if (blockIdx.x < 44) {
    int sidx = (blockIdx.x - 12) * 256 + tid;  // 0..8191
    int s = sidx & 1023;
    int kg = (sidx >> 10) & 3;
    int ks = sidx >> 12;
    int L = (s & ~63) + 4 * (s & 15) + ((s >> 4) & 3);
#pragma unroll
    for (int e = 0; e < 8; ++e) {
      int k = ks * 32 + kg * 8 + e;
      bp[((size_t)((ks * 4 + kg) * P_N + s)) * 8 + e] = f2bf(fcW[k * P_N + L]);
    }
  } else {
    int u = blockIdx.x - 44;
    __shared__ float pu[H_N];
    if (tid < H_N) pu[tid] = user_emb[active_user[u] * H_N + tid];
    __syncthreads();
    for (int p = tid; p < P_N; p += 256) {
      float acc = fcb[p];
#pragma unroll
      for (int k = 0; k < H_N; ++k) acc += pu[k] * fcW[(H_N + k) * P_N + p];
      ub[u * P_N + p] = acc;
    }
  }
}

// ---- gx precompute (TRANSPOSED): C[gate][user]; A = Wx^T frag, B = emb ------
__global__ __launch_bounds__(256) void k_gx(
    const int* __restrict__ x, const float* __restrict__ poi_emb,
    const short* __restrict__ wxp, const float* __restrict__ b,
    char* __restrict__ gxp) {
  int wave = threadIdx.x >> 6, lane = threadIdx.x & 63;
  int lr = lane & 15, lk = lane >> 4;
  int tile = blockIdx.x * 4 + wave;   // 0..8191
  int row = tile * 16 + lr;           // flat t*512+u; user = lr
  int xv = x[row];
  const float* pb = poi_emb + (size_t)xv * H_N + lk * 8;
  float4 v0 = *(const float4*)pb, v1 = *(const float4*)(pb + 4);
  float4 v2 = *(const float4*)(pb + 32), v3 = *(const float4*)(pb + 36);
  short8 ax0 = pack8(v0, v1), ax1 = pack8(v2, v3);  // B-frag: col=user, k=h
#pragma unroll
  for (int j = 0; j < 12; ++j) {
    f32x4 acc;
#pragma unroll
    for (int e = 0; e < 4; ++e) acc[e] = b[16 * j + 4 * lk + e];
    short8 bf0 = *(const short8*)&wxp[((size_t)((0 * 4 + lk) * 192 + 16 * j + lr)) * 8];
    short8 bf1 = *(const short8*)&wxp[((size_t)((1 * 4 + lk) * 192 + 16 * j + lr)) * 8];
    acc = MFMA(bf0, ax0, acc, 0, 0, 0);   // A = Wx^T frag, B = emb frag
    acc = MFMA(bf1, ax1, acc, 0, 0, 0);
    uint2 pk;
    pk.x = cvtpk(acc[0], acc[1]);
    pk.y = cvtpk(acc[2], acc[3]);
    *(uint2*)(gxp + (((size_t)tile * 12 + j) * 64 + lane) * 8) = pk;
  }
}

// ---- GRU scan (transposed) + LDS-staged coalesced flush ---------------------
__global__ __launch_bounds__(256) void k_scan3(
    const char* __restrict__ gxp, const float* __restrict__ h0,
    const short* __restrict__ whp, short* __restrict__ out_tr,
    float* __restrict__ hT) {
  int ublk = blockIdx.x;
  int u0 = ublk * 16;
  int tid = threadIdx.x;
  int w = tid >> 6, lane = tid & 63, lr = lane & 15, q = lane >> 4;
  __shared__ __align__(16) unsigned short h16[2][16][68];   // ping-pong h
  __shared__ __align__(16) unsigned short flsh[16][520];    // flush stage, 1040B/user
  int sgr = 16 * w, sgz = 64 + 16 * w, sgn = 128 + 16 * w;
  short8 fhr[2], fhz[2], fhn[2];  // A-frags (Wh^T): row=gate, k=h
#pragma unroll
  for (int ks = 0; ks < 2; ++ks) {
    size_t base = (size_t)((ks * 4 + q) * 192) * 8;
    fhr[ks] = *(const short8*)&whp[base + (size_t)(sgr + lr) * 8];
    fhz[ks] = *(const short8*)&whp[base + (size_t)(sgz + lr) * 8];
    fhn[ks] = *(const short8*)&whp[base + (size_t)(sgn + lr) * 8];
  }
  const char* gbase = gxp + (((size_t)ublk * 12 + w) * 64 + lane) * 8;
  uint2 pr0, pr1, pr2, pr3, pr4, pr5, pr6, pr7;
  uint2 pz0, pz1, pz2, pz3, pz4, pz5, pz6, pz7;
  uint2 pn0, pn1, pn2, pn3, pn4, pn5, pn6, pn7;
  float hp[4];
  short8 bh0, bh1;
  float hb[4][8];  // static-index only
#define PF(sl, tt) { size_t o = (size_t)(tt) * 196608; \
    pr##sl = *(const uint2*)(gbase + o); \
    pz##sl = *(const uint2*)(gbase + o + 2048); \
    pn##sl = *(const uint2*)(gbase + o + 4096); }
#define GATE(E, TB) { \
      float r = fastrcp(1.f + __expf(-accr[E])); \
      float z = fastrcp(1.f + __expf(-accz[E])); \
      float npre = __builtin_fmaf(r, accnh[E], accnx[E]); \
      float e2 = __expf(2.f * npre); \
      float n = 1.f - 2.f * fastrcp(e2 + 1.f); \
      float hn = __builtin_fmaf(z, n - hp[E], hp[E]); \
      hp[E] = hn; \
      hb[E][TB] = hn; }
#define BODY(TB, SL) { \
      f32x4 accr = {bfu_lo(pr##SL.x), bfu_hi(pr##SL.x), bfu_lo(pr##SL.y), bfu_hi(pr##SL.y)}; \
      f32x4 accz = {bfu_lo(pz##SL.x), bfu_hi(pz##SL.x), bfu_lo(pz##SL.y), bfu_hi(pz##SL.y)}; \
      f32x4 accnx = {bfu_lo(pn##SL.x), bfu_hi(pn##SL.x), bfu_lo(pn##SL.y), bfu_hi(pn##SL.y)}; \
      f32x4 accnh = {0.f, 0.f, 0.f, 0.f}; \
      int tpf = t8 + TB + 8; if (tpf > 255) tpf = 255; \
      PF(SL, tpf) \
      accr = MFMA(fhr[0], bh0, accr, 0, 0, 0); \
      accr = MFMA(fhr[1], bh1, accr, 0, 0, 0); \
      accz = MFMA(fhz[0], bh0, accz, 0, 0, 0); \
      accz = MFMA(fhz[1], bh1, accz, 0, 0, 0); \
      accnh = MFMA(fhn[0], bh0, accnh, 0, 0, 0); \
      accnh = MFMA(fhn[1], bh1, accnh, 0, 0, 0); \
      GATE(0, TB) GATE(1, TB) GATE(2, TB) GATE(3, TB) \
      { \
        uint2 pk; \
        pk.x = cvtpk(hp[0], hp[1]); \
        pk.y = cvtpk(hp[2], hp[3]); \
        *(uint2*)&h16[(TB) & 1][lr][16 * w + 4 * q] = pk; \
      } \
      LGKM_BARRIER(); \
      bh0 = *(const short8*)&h16[(TB) & 1][lr][8 * q]; \
      bh1 = *(const short8*)&h16[(TB) & 1][lr][32 + 8 * q]; }
#pragma unroll
  for (int e = 0; e < 4; ++e)
    hp[e] = h0[(size_t)(u0 + lr) * H_N + 16 * w + 4 * q + e];
  {
    uint2 pk;
    pk.x = cvtpk(hp[0], hp[1]);
    pk.y = cvtpk(hp[2], hp[3]);
    *(uint2*)&h16[1][lr][16 * w + 4 * q] = pk;
  }
  __syncthreads();
  bh0 = *(const short8*)&h16[1][lr][8 * q];
  bh1 = *(const short8*)&h16[1][lr][32 + 8 * q];
  PF(0, 0) PF(1, 1) PF(2, 2) PF(3, 3) PF(4, 4) PF(5, 5) PF(6, 6) PF(7, 7)
  for (int t8 = 0; t8 < T_N; t8 += 8) {
    BODY(0, 0) BODY(1, 1) BODY(2, 2) BODY(3, 3)
    BODY(4, 4) BODY(5, 5) BODY(6, 6) BODY(7, 7)
    // flush: stage hb -> flsh (bf16), barrier, coalesced 1KB/wave readout
    {
#pragma unroll
      for (int e = 0; e < 4; ++e) {
        u32x4 pk;
        pk[0] = cvtpk(hb[e][0], hb[e][1]);
        pk[1] = cvtpk(hb[e][2], hb[e][3]);
        pk[2] = cvtpk(hb[e][4], hb[e][5]);
        pk[3] = cvtpk(hb[e][6], hb[e][7]);
        *(u32x4*)&flsh[lr][(16 * w + 4 * q + e) * 8] = pk;
      }
      LGKM_BARRIER();
      int tb = t8 >> 3;
#pragma unroll
      for (int pp = 0; pp < 4; ++pp) {
        int p = pp * 256 + tid;
        int uu = p >> 6, hh = p & 63;
        u32x4 v = *(const u32x4*)&flsh[uu][hh * 8];
        __builtin_nontemporal_store(
            v, (u32x4*)&out_tr[((((size_t)(u0 + uu)) * 32 + tb) * 64 + hh) * 8]);
      }
    }
  }
#pragma unroll
  for (int e = 0; e < 4; ++e)
    hT[(size_t)(u0 + lr) * H_N + 16 * w + 4 * q + e] = hp[e];  // exact f32
}

// ---- decay-weighted sum as causal MFMA GEMM; factored trig/exp w-compute ----
__global__ __launch_bounds__(256, 4) void k_stage2(
    const float* __restrict__ t, const float* __restrict__ s,
    const short* __restrict__ out_tr, short* __restrict__ apk) {
  int u = blockIdx.x;
  int tid = threadIdx.x;
  __shared__ __align__(16) unsigned short wlT[16][264];  // [i'][j] bf16
  __shared__ __align__(8) float csU[T_N][2];
  __shared__ __align__(8) float seU[T_N][2];
  __shared__ float eU[T_N];
  float cj, sj, Fj, sx, sy;
  {
    int jr = tid;
    float tj = t[jr * U_N + u];
    cj = __cosf(tj * 7.2722052166430395e-05f);
    sj = __sinf(tj * 7.2722052166430395e-05f);
    float ej = __expf(tj * -1.1574074074074074e-06f);
    Fj = __expf(tj * 1.1574074074074074e-06f);
    csU[jr][0] = cj; csU[jr][1] = sj;
    eU[jr] = ej;
    sx = s[((size_t)jr * U_N + u) * 2];
    sy = s[((size_t)jr * U_N + u) * 2 + 1];
    seU[jr][0] = sx; seU[jr][1] = sy;
  }
  __syncthreads();
  int lane = tid & 63, wv = tid >> 6;
  int lr = lane & 15, lk = lane >> 4;
  int j = tid;
  const short* obase = out_tr + (size_t)u * 32 * 64 * 8;  // [tb][h][8]
  short8 ones;
#pragma unroll
  for (int e = 0; e < 8; ++e) ones[e] = (short)0x3F80;
  for (int c = 0; c < 16; ++c) {
    int nk = (c + 2) >> 1;
    if (wv * 64 < nk * 32) {
#pragma unroll
      for (int iqq = 0; iqq < 16; ++iqq) {
        int i = c * 16 + iqq;
        float ci = csU[i][0], si = csU[i][1];
        float ei = eU[i];
        float dx = seU[i][0] - sx, dy = seU[i][1] - sy;
        float dsn = fastsqrt(__builtin_fmaf(dx, dx, dy * dy));
        float fs = __expf(-100.0f * dsn);
        float ctm = __builtin_fmaf(ci, cj, si * sj);
        float ft2 = __builtin_fmaf(0.5f, ctm, 0.5f);
        float ww = __builtin_fmaf(ft2 * (ei * Fj), fs, 1e-10f);
        ww = (j <= i) ? ww : 0.0f;
        wlT[iqq][j] = (unsigned short)cvtpk(ww, ww);
      }
    }
    __syncthreads();  // B1
    f32x4 acc = {0.f, 0.f, 0.f, 0.f};
    f32x4 acc1 = {0.f, 0.f, 0.f, 0.f};
    for (int kk = 0; kk < nk; ++kk) {
      short8 aw = *(const short8*)&wlT[lr][kk * 32 + 8 * lk];
      short8 bo = *(const short8*)&obase[(((kk * 4 + lk) * 64) + 16 * wv + lr) * 8];
      acc = MFMA(aw, bo, acc, 0, 0, 0);
      acc1 = MFMA(aw, ones, acc1, 0, 0, 0);
    }
#pragma unroll
    for (int e = 0; e < 4; ++e) {
      int i = c * 16 + 4 * lk + e;
      float val = acc[e] * fastrcp(acc1[e]);
      apk[((size_t)i * U_N + u) * H_N + 16 * wv + lr] = f2bf(val);
    }
    __syncthreads();  // B2
  }
}

// ---- FC: grid dim3(1024,8) bm-fastest -> per-XCD apk slice is L2-resident ---
__global__ __launch_bounds__(256) void k_fc(
    const short* __restrict__ apk, const short* __restrict__ Bp,
    const float* __restrict__ ub, float* __restrict__ C) {
  int bm = blockIdx.x, bn = blockIdx.y;
  int tid = threadIdx.x;
  int wave = tid >> 6, lane = tid & 63;
  int wm = wave >> 1, wn = wave & 1;
  int row0 = bm * 128 + wm * 64;
  int col0 = bn * 128 + wn * 64;
  int lr = lane & 15, lk = lane >> 4;
  f32x4 acc[4][4] = {};
#pragma unroll
  for (int ks = 0; ks < 2; ++ks) {
    short8 af[4];
#pragma unroll
    for (int m = 0; m < 4; ++m)
      af[m] = *(const short8*)&apk[((size_t)(row0 + m * 16 + lr)) * H_N + ks * 32 + lk * 8];
#pragma unroll
    for (int n = 0; n < 4; ++n) {
      short8 bf = *(const short8*)&Bp[((size_t)((ks * 4 + lk) * P_N + col0 + n * 16 + lr)) * 8];
#pragma unroll
      for (int m = 0; m < 4; ++m)
        acc[m][n] = MFMA(af[m], bf, acc[m][n], 0, 0, 0);
    }
  }
#pragma unroll
  for (int m = 0; m < 4; ++m) {
    int rbase = row0 + m * 16 + lk * 4;
#pragma unroll
    for (int r = 0; r < 4; ++r) {
      int row = rbase + r;
      int uu = row & (U_N - 1);
      f32x4 ubv = *(const f32x4*)&ub[(size_t)uu * P_N + col0 + 4 * lr];
      f32x4 v;
      v[0] = acc[m][0][r] + ubv[0];
      v[1] = acc[m][1][r] + ubv[1];
      v[2] = acc[m][2][r] + ubv[2];
      v[3] = acc[m][3][r] + ubv[3];
      __builtin_nontemporal_store(v, (f32x4*)&C[(size_t)row * P_N + col0 + 4 * lr]);
    }
  }
}

extern "C" void kernel_launch(void* const* d_in, const int* in_sizes, int n_in,
                              void* d_out, int out_size, void* d_ws, size_t ws_size,
                              hipStream_t stream) {
  const int*   x           = (const int*)d_in[0];
  const float* t           = (const float*)d_in[1];
  const float* s           = (const float*)d_in[3];
  const float* h0          = (const float*)d_in[5];
  const int*   active_user = (const int*)d_in[6];
  const float* poi_emb     = (const float*)d_in[7];
  const float* user_emb    = (const float*)d_in[8];
  const float* Wx          = (const float*)d_in[9];
  const float* Wh          = (const float*)d_in[10];
  const float* b           = (const float*)d_in[11];
  const float* fcW         = (const float*)d_in[12];
  const float* fcb         = (const float*)d_in[13];

  float* y_out = (float*)d_out;
  float* hT = y_out + (size_t)T_N * U_N * P_N;

  char* ws = (char*)d_ws;
  short* out_tr = (short*)ws;                           // 16,777,216 B
  char*  gxp    = ws + 16777216;                        // 50,331,648 B (dead after scan)
  short* apk    = (short*)(ws + 16777216);              // OVERLAPS gxp
  float* ub     = (float*)(ws + 67108864);              // 2,097,152 B
  short* bp     = (short*)(ws + 69206016);              // 131,072 B
  short* wxp    = (short*)(ws + 69337088);              // 24,576 B
  short* whp    = (short*)(ws + 69361664);              // 24,576 B

  k_pack<<<556, 256, 0, stream>>>(Wx, Wh, fcW, active_user, user_emb, fcb,
                                  wxp, whp, bp, ub);
  k_gx<<<2048, 256, 0, stream>>>(x, poi_emb, wxp, b, gxp);
  k_scan3<<<32, 256, 0, stream>>>(gxp, h0, whp, out_tr, hT);
  k_stage2<<<U_N, 256, 0, stream>>>(t, s, out_tr, apk);
  k_fc<<<dim3(1024, 8), 256, 0, stream>>>(apk, bp, ub, y_out);
}